// Round 6
// baseline (331.363 us; speedup 1.0000x reference)
//
#include <hip/hip_runtime.h>
#include <hip/hip_bf16.h>
#include <cmath>

// ---------------------------------------------------------------------------
// NPerTokenSwishGLU_Basis — fused f16-MFMA implementation (gfx950), round 6.
//
// R5 post-mortem: total flat because the swapped-major prep scattered its
// stores (64x 16B chunks @16KB stride per wave). R6:
//  (1) prep rewritten as LDS-tile transpose, coalesced on BOTH sides
//      (64B-contiguous reads, 1KB-contiguous writes, conflict-free strides).
//  (2) up_fast: P A-frag loads register-double-buffered one full iteration
//      ahead (grid caps occupancy at 2 waves/SIMD, so the VGPR cost is free).
// Layout/gating unchanged: P1@0 P2@16M P3@32M Hp@48M (52 MiB, proven);
// Rp/Np overlay P1/P2 for the down partials.
// ---------------------------------------------------------------------------

typedef _Float16 half8 __attribute__((ext_vector_type(8)));
typedef _Float16 half4 __attribute__((ext_vector_type(4)));
typedef float    f32x4 __attribute__((ext_vector_type(4)));

#define MFMA_F16 __builtin_amdgcn_mfma_f32_16x16x32_f16

static constexpr size_t OFF_P1 = 0;            // 16 MiB; Rp overlay (down)
static constexpr size_t OFF_P2 = 16777216;     // 16 MiB; Np overlay (down)
static constexpr size_t OFF_P3 = 33554432;     // 16 MiB
static constexpr size_t OFF_HP = 50331648;     // 4 MiB
static constexpr size_t WS_FAST = OFF_HP + 4194304;   // 54,525,952

// ---------------------------------------------------------------------------
// prep (two-sided coalesced transpose):
//   z=0,1: src wg/wu (K,512,1024)=[k][d][f] -> P[f][d][k]  (minor=d, major=f)
//   z=2  : src wd    (K,1024,512)=[k][f][d] -> P3[d][f][k] (minor=f, major=d)
// Block: 32-minor x 16-major x all 16 k.  grid.x = 1024 per z.
// Reads: 16-float (64 B) contiguous row segments. Writes: consecutive lanes
// -> consecutive minor -> 32B-contiguous chunks (1 KB / 32 lanes).
// LDS strides 544(k) / 17(minor): both sides <=2 lanes/bank.
// ---------------------------------------------------------------------------
__global__ __launch_bounds__(256) void prep_basis_all(
    const float* __restrict__ wg, const float* __restrict__ wu,
    const float* __restrict__ wd,
    _Float16* __restrict__ P1, _Float16* __restrict__ P2,
    _Float16* __restrict__ P3)
{
    int z = blockIdx.y;
    const float* src = (z == 0) ? wg : (z == 1) ? wu : wd;
    _Float16*    dst = (z == 0) ? P1 : (z == 1) ? P2 : P3;
    int Amin = (z == 2) ? 1024 : 512;    // minor-dim size
    int Bmaj = (z == 2) ? 512 : 1024;    // major-dim size
    int nM = Bmaj >> 4;                  // major tiles (16 wide)
    int m0 = (blockIdx.x / nM) * 32;     // minor base
    int M0 = (blockIdx.x % nM) * 16;     // major base

    __shared__ float S[16 * 544];        // [k][minor*17 + major]
    int t = threadIdx.x;

    // load: 8 passes x 2 k; 128 threads per k cover 32 rows x 16 cols
    int row = (t >> 2) & 31;             // minor offset
    int cg  = t & 3;                     // col group (4 floats)
    int khi = t >> 7;                    // 0/1
#pragma unroll
    for (int p = 0; p < 8; ++p) {
        int k = p * 2 + khi;
        f32x4 v = *(const f32x4*)(
            src + (size_t)k * Amin * Bmaj + (size_t)(m0 + row) * Bmaj + M0 + cg * 4);
#pragma unroll
        for (int j = 0; j < 4; ++j)
            S[k * 544 + row * 17 + cg * 4 + j] = v[j];
    }
    __syncthreads();

    // write: 2 passes; lane -> (minor = t&31, major = (t>>5) + 8*pass)
    int mn = t & 31, mjb = t >> 5;
#pragma unroll
    for (int q = 0; q < 2; ++q) {
        int mj = mjb + q * 8;
        half8 v0, v1;
#pragma unroll
        for (int k = 0; k < 8; ++k) v0[k] = (_Float16)S[k * 544 + mn * 17 + mj];
#pragma unroll
        for (int k = 0; k < 8; ++k) v1[k] = (_Float16)S[(k + 8) * 544 + mn * 17 + mj];
        _Float16* out = dst + ((size_t)(M0 + mj) * Amin + m0 + mn) * 16;
        *(half8*)out       = v0;
        *(half8*)(out + 8) = v1;
    }
}

// ---------------------------------------------------------------------------
// up_fast: 512 blocks = 8 l-groups x 64 f-tiles, 256 threads.
// P A-frags register-double-buffered one iteration ahead.
// ---------------------------------------------------------------------------
struct PA { half8 v[2][4][2]; };   // [mat][fl][dg]

__global__ __launch_bounds__(256, 2) void up_fast(
    const _Float16* __restrict__ P1, const _Float16* __restrict__ P2,
    const float* __restrict__ x,
    const float* __restrict__ tc1, const float* __restrict__ tc2,
    const float* __restrict__ usp, const float* __restrict__ vsp,
    _Float16* __restrict__ Hp)
{
    int lg = blockIdx.x >> 6;
    int f0 = (blockIdx.x & 63) * 16;
    int tid = threadIdx.x;
    int w = tid >> 6, lane = tid & 63;
    int n = lane & 15, kc = lane >> 4;

    __shared__ __align__(16) _Float16 Wt[2][16 * 584];  // [mat][l*584+f*36+d]
    __shared__ float CN[2 * 256];

    if (tid < 32) {
        int s = tid >> 4, ll = tid & 15;
        const float* row = (s ? tc2 : tc1) + (size_t)(lg * 16 + ll) * 16;
        float e[16], m = -1e30f, sum = 0.f;
#pragma unroll
        for (int k = 0; k < 16; ++k) m = fmaxf(m, row[k]);
#pragma unroll
        for (int k = 0; k < 16; ++k) { e[k] = __expf(row[k] - m); sum += e[k]; }
        float r = 1.f / sum;
#pragma unroll
        for (int k = 0; k < 16; ++k) CN[s * 256 + ll * 16 + k] = e[k] * r;
    }
    __syncthreads();

    half8 cf1 = { 0, 0, 0, 0, 0, 0, 0, 0 };
    half8 cf2 = { 0, 0, 0, 0, 0, 0, 0, 0 };
    if (kc < 2) {
#pragma unroll
        for (int j = 0; j < 8; ++j) {
            cf1[j] = (_Float16)CN[0 * 256 + n * 16 + kc * 8 + j];
            cf2[j] = (_Float16)CN[1 * 256 + n * 16 + kc * 8 + j];
        }
    }

    f32x4 zf = { 0.f, 0.f, 0.f, 0.f };
    f32x4 aU[4], aV[4];
#pragma unroll
    for (int i = 0; i < 4; ++i) { aU[i] = zf; aV[i] = zf; }
    float nsqU[4] = { 0.f, 0.f, 0.f, 0.f };
    float nsqV[4] = { 0.f, 0.f, 0.f, 0.f };
    half8 xf[4];
    PA paA, paB;

    auto load_pa = [&](int it, PA& dstp) {
        int d0 = it * 32;
#pragma unroll
        for (int m = 0; m < 2; ++m) {
            const _Float16* P = m ? P2 : P1;
#pragma unroll
            for (int fl = 0; fl < 4; ++fl)
#pragma unroll
                for (int dg = 0; dg < 2; ++dg) {
                    half8 a = { 0, 0, 0, 0, 0, 0, 0, 0 };
                    if (kc < 2)
                        a = *(const half8*)(P +
                            ((size_t)(f0 + w * 4 + fl) * 512 + d0 + dg * 16 + n) * 16 + kc * 8);
                    dstp.v[m][fl][dg] = a;
                }
        }
    };
    auto load_xf = [&](int it) {
        int d0 = it * 32;
#pragma unroll
        for (int li = 0; li < 4; ++li) {
            int l = lg * 16 + w * 4 + li;
            const float* xp = x + ((size_t)n * 128 + l) * 512 + d0 + kc * 8;
            f32x4 v0 = *(const f32x4*)xp;
            f32x4 v1 = *(const f32x4*)(xp + 4);
            half8 h = { (_Float16)v0[0], (_Float16)v0[1], (_Float16)v0[2],
                        (_Float16)v0[3], (_Float16)v1[0], (_Float16)v1[1],
                        (_Float16)v1[2], (_Float16)v1[3] };
            xf[li] = h;
        }
    };
    auto consume = [&]() {
#pragma unroll
        for (int li = 0; li < 4; ++li) {
            int l = w * 4 + li;
            half8 wU = *(const half8*)(&Wt[0][l * 584 + n * 36 + kc * 8]);
            half8 wV = *(const half8*)(&Wt[1][l * 584 + n * 36 + kc * 8]);
            aU[li] = MFMA_F16(xf[li], wU, aU[li], 0, 0, 0);
            aV[li] = MFMA_F16(xf[li], wV, aV[li], 0, 0, 0);
        }
    };
    auto mix = [&](PA& cur) {
#pragma unroll
        for (int fl = 0; fl < 4; ++fl) {
            int f_l = w * 4 + fl;
#pragma unroll
            for (int dg = 0; dg < 2; ++dg) {
                f32x4 c1 = MFMA_F16(cur.v[0][fl][dg], cf1, zf, 0, 0, 0);
                nsqU[fl] += c1[0] * c1[0] + c1[1] * c1[1]
                          + c1[2] * c1[2] + c1[3] * c1[3];
                half4 h1 = { (_Float16)c1[0], (_Float16)c1[1],
                             (_Float16)c1[2], (_Float16)c1[3] };
                *(half4*)(&Wt[0][n * 584 + f_l * 36 + dg * 16 + kc * 4]) = h1;
                f32x4 c2 = MFMA_F16(cur.v[1][fl][dg], cf2, zf, 0, 0, 0);
                nsqV[fl] += c2[0] * c2[0] + c2[1] * c2[1]
                          + c2[2] * c2[2] + c2[3] * c2[3];
                half4 h2 = { (_Float16)c2[0], (_Float16)c2[1],
                             (_Float16)c2[2], (_Float16)c2[3] };
                *(half4*)(&Wt[1][n * 584 + f_l * 36 + dg * 16 + kc * 4]) = h2;
            }
        }
    };

    load_pa(0, paA);
    for (int j = 0; j < 8; ++j) {
        {   // it = 2j : mix from paA, prefetch into paB
            int it = 2 * j;
            if (it < 15) load_pa(it + 1, paB);
            if (it > 0) consume();
            load_xf(it);
            __syncthreads();
            mix(paA);
            __syncthreads();
        }
        {   // it = 2j+1 : mix from paB, prefetch into paA
            int it = 2 * j + 1;
            if (it < 15) load_pa(it + 1, paA);
            consume();
            load_xf(it);
            __syncthreads();
            mix(paB);
            __syncthreads();
        }
    }
    consume();   // tail: chunk 15

    // ---- norms reduce ----
#pragma unroll
    for (int fl = 0; fl < 4; ++fl) {
        float vU = nsqU[fl], vV = nsqV[fl];
        vU += __shfl_xor(vU, 16); vU += __shfl_xor(vU, 32);
        vV += __shfl_xor(vV, 16); vV += __shfl_xor(vV, 32);
        if (kc == 0) {
            CN[0 * 256 + n * 16 + w * 4 + fl] = vU;
            CN[1 * 256 + n * 16 + w * 4 + fl] = vV;
        }
    }
    __syncthreads();

    int f = f0 + n;
    float usv = fabsf(usp[f]);
    float vsv = fabsf(vsp[f]) * 22.627416997969522f;   // sqrt(512)
#pragma unroll
    for (int li = 0; li < 4; ++li) {
        int lgl = lg * 16 + w * 4 + li;
        float r1 = 1.f / fmaxf(sqrtf(CN[0 * 256 + (w * 4 + li) * 16 + n]), 1e-12f);
        float r2 = 1.f / fmaxf(sqrtf(CN[1 * 256 + (w * 4 + li) * 16 + n]), 1e-12f);
#pragma unroll
        for (int i = 0; i < 4; ++i) {
            float u = aU[li][i] * r1;
            float v = aV[li][i] * r2;
            float zz = vsv * v;
            float sil = zz / (1.f + __expf(-zz));
            float h = sil * (usv * u);
            Hp[((size_t)lgl * 16 + kc * 4 + i) * 1024 + f] = (_Float16)h;
        }
    }
}

// ---------------------------------------------------------------------------
// down_fast: 1024 blocks = 4 f-quarters x 8 l-groups x 32 d-tiles. (as R5)
// ---------------------------------------------------------------------------
__global__ __launch_bounds__(256, 2) void down_fast(
    const _Float16* __restrict__ P3, const float* __restrict__ tc3,
    const _Float16* __restrict__ Hp,
    float* __restrict__ Rp, float* __restrict__ Np)
{
    int zh = blockIdx.x >> 8;          // 0..3
    int rem = blockIdx.x & 255;
    int lg = rem >> 5;
    int d0 = (rem & 31) * 16;
    int tid = threadIdx.x;
    int w = tid >> 6, lane = tid & 63;
    int n = lane & 15, kc = lane >> 4;

    __shared__ __align__(16) _Float16 Wt[16 * 584];    // [l*584 + d*36 + f]
    __shared__ float CN[256];

    if (tid < 16) {
        const float* row = tc3 + (size_t)(lg * 16 + tid) * 16;
        float e[16], m = -1e30f, sum = 0.f;
#pragma unroll
        for (int k = 0; k < 16; ++k) m = fmaxf(m, row[k]);
#pragma unroll
        for (int k = 0; k < 16; ++k) { e[k] = __expf(row[k] - m); sum += e[k]; }
        float r = 1.f / sum;
#pragma unroll
        for (int k = 0; k < 16; ++k) CN[tid * 16 + k] = e[k] * r;
    }
    __syncthreads();

    half8 cf3 = { 0, 0, 0, 0, 0, 0, 0, 0 };
    if (kc < 2) {
#pragma unroll
        for (int j = 0; j < 8; ++j)
            cf3[j] = (_Float16)CN[n * 16 + kc * 8 + j];
    }

    f32x4 zf = { 0.f, 0.f, 0.f, 0.f };
    f32x4 aO[4];
#pragma unroll
    for (int i = 0; i < 4; ++i) aO[i] = zf;
    float nsqD[4] = { 0.f, 0.f, 0.f, 0.f };
    half8 hf[4];
    half8 pa[4][2];

    for (int it = 0; it < 8; ++it) {
        int f0 = zh * 256 + it * 32;
#pragma unroll
        for (int dl = 0; dl < 4; ++dl) {
#pragma unroll
            for (int fg = 0; fg < 2; ++fg) {
                half8 a = { 0, 0, 0, 0, 0, 0, 0, 0 };
                if (kc < 2)
                    a = *(const half8*)(P3 +
                        ((size_t)(d0 + w * 4 + dl) * 1024 + f0 + fg * 16 + n) * 16 + kc * 8);
                pa[dl][fg] = a;
            }
        }
        if (it > 0) {
#pragma unroll
            for (int li = 0; li < 4; ++li) {
                int l = w * 4 + li;
                half8 wf = *(const half8*)(&Wt[l * 584 + n * 36 + kc * 8]);
                aO[li] = MFMA_F16(hf[li], wf, aO[li], 0, 0, 0);
            }
        }
#pragma unroll
        for (int li = 0; li < 4; ++li) {
            int l = lg * 16 + w * 4 + li;
            hf[li] = *(const half8*)(Hp + ((size_t)l * 16 + n) * 1024 + f0 + kc * 8);
        }
        __syncthreads();
#pragma unroll
        for (int dl = 0; dl < 4; ++dl) {
            int d_l = w * 4 + dl;
#pragma unroll
            for (int fg = 0; fg < 2; ++fg) {
                f32x4 cw = MFMA_F16(pa[dl][fg], cf3, zf, 0, 0, 0);
                nsqD[dl] += cw[0] * cw[0] + cw[1] * cw[1]
                          + cw[2] * cw[2] + cw[3] * cw[3];
                half4 h4 = { (_Float16)cw[0], (_Float16)cw[1],
                             (_Float16)cw[2], (_Float16)cw[3] };
                *(half4*)(&Wt[n * 584 + d_l * 36 + fg * 16 + kc * 4]) = h4;
            }
        }
        __syncthreads();
    }
#pragma unroll
    for (int li = 0; li < 4; ++li) {
        int l = w * 4 + li;
        half8 wf = *(const half8*)(&Wt[l * 584 + n * 36 + kc * 8]);
        aO[li] = MFMA_F16(hf[li], wf, aO[li], 0, 0, 0);
    }

#pragma unroll
    for (int dl = 0; dl < 4; ++dl) {
        float v = nsqD[dl];
        v += __shfl_xor(v, 16); v += __shfl_xor(v, 32);
        if (kc == 0)
            Np[(size_t)zh * 65536 + (size_t)(lg * 16 + n) * 512 + d0 + w * 4 + dl] = v;
    }
#pragma unroll
    for (int li = 0; li < 4; ++li) {
        int lgl = lg * 16 + w * 4 + li;
#pragma unroll
        for (int i = 0; i < 4; ++i)
            Rp[(size_t)zh * 1048576 +
               ((size_t)(kc * 4 + i) * 128 + lgl) * 512 + d0 + n] = aO[li][i];
    }
}

// ---------------------------------------------------------------------------
__global__ __launch_bounds__(128) void final_combine(
    const float* __restrict__ Rp, const float* __restrict__ Np,
    float* __restrict__ out)
{
    int rid = blockIdx.x;              // b*128 + l
    int l = rid & 127;
    int t = threadIdx.x;
    f32x4 r = { 0.f, 0.f, 0.f, 0.f };
    f32x4 nn = { 0.f, 0.f, 0.f, 0.f };
#pragma unroll
    for (int zh = 0; zh < 4; ++zh) {
        f32x4 rz = *(const f32x4*)(Rp + (size_t)zh * 1048576 + (size_t)rid * 512 + t * 4);
        f32x4 nz = *(const f32x4*)(Np + (size_t)zh * 65536 + (size_t)l * 512 + t * 4);
#pragma unroll
        for (int j = 0; j < 4; ++j) { r[j] += rz[j]; nn[j] += nz[j]; }
    }
    f32x4 y;
#pragma unroll
    for (int j = 0; j < 4; ++j) {
        float rr = 1.f / fmaxf(sqrtf(fmaxf(nn[j], 0.f)), 1e-12f);
        y[j] = r[j] * rr;
    }
    float s = y[0] * y[0] + y[1] * y[1] + y[2] * y[2] + y[3] * y[3];
#pragma unroll
    for (int off = 32; off > 0; off >>= 1) s += __shfl_down(s, off);
    __shared__ float sred[2];
    if ((t & 63) == 0) sred[t >> 6] = s;
    __syncthreads();
    float rr = 1.f / fmaxf(sqrtf(sred[0] + sred[1]), 1e-12f);
    f32x4 o = { y[0] * rr, y[1] * rr, y[2] * rr, y[3] * rr };
    *(f32x4*)(out + (size_t)rid * 512 + t * 4) = o;
}

// ===========================================================================
// SLOW FALLBACK (round-2 kernels, proven) — used when ws_size < WS_FAST
// ===========================================================================
__global__ __launch_bounds__(256) void up_kernel(
    const float* __restrict__ x,
    const float* __restrict__ wg, const float* __restrict__ wu,
    const float* __restrict__ tc1, const float* __restrict__ tc2,
    const float* __restrict__ usp, const float* __restrict__ vsp,
    _Float16* __restrict__ Hp)
{
    int lg = blockIdx.x >> 6;
    int f0 = (blockIdx.x & 63) * 16;
    int tid = threadIdx.x;
    int w = tid >> 6, lane = tid & 63;
    int n = lane & 15, kc = lane >> 4;

    __shared__ __align__(16) _Float16 Xt[256 * 40];
    __shared__ __align__(16) _Float16 Bh[32 * 16 * 24];
    __shared__ __align__(16) _Float16 Wt[16 * 528];
    __shared__ float CN[2 * 16 * 16];

    if (tid < 32) {
        int s = tid >> 4, ll = tid & 15;
        const float* row = (s ? tc2 : tc1) + (size_t)(lg * 16 + ll) * 16;
        float e[16], m = -1e30f, sum = 0.f;
#pragma unroll
        for (int k = 0; k < 16; ++k) m = fmaxf(m, row[k]);
#pragma unroll
        for (int k = 0; k < 16; ++k) { e[k] = __expf(row[k] - m); sum += e[k]; }
        float r = 1.f / sum;
#pragma unroll
        for (int k = 0; k < 16; ++k) CN[s * 256 + ll * 16 + k] = e[k] * r;
    }
    __syncthreads();

    half8 cf1 = { 0, 0, 0, 0, 0, 0, 0, 0 };
    half8 cf2 = { 0, 0, 0, 0, 0, 0, 0, 0 };
    if (kc < 2) {
#pragma unroll
        for (int j = 0; j < 8; ++j) {
            cf1[j] = (_Float16)CN[0 * 256 + n * 16 + kc * 8 + j];
            cf2[j] = (_Float16)CN[1 * 256 + n * 16 + kc * 8 + j];
        }
    }

    f32x4 zf = { 0.f, 0.f, 0.f, 0.f };
    f32x4 aU[4], aV[4];
#pragma unroll
    for (int i = 0; i < 4; ++i) { aU[i] = zf; aV[i] = zf; }
    float nsqU[4] = { 0.f, 0.f, 0.f, 0.f };
    float nsqV[4] = { 0.f, 0.f, 0.f, 0.f };

    for (int it = 0; it < 16; ++it) {
        int d0 = it * 32;
#pragma unroll
        for (int p = 0; p < 8; ++p) {
            int r = p * 32 + (tid >> 3);
            int fj = tid & 7;
            int ll = r >> 4, b = r & 15;
            f32x4 v = *(const f32x4*)(
                x + ((size_t)(b * 128 + lg * 16 + ll) * 512 + d0 + fj * 4));
            half4 h = { (_Float16)v[0], (_Float16)v[1],
                        (_Float16)v[2], (_Float16)v[3] };
            *(half4*)(&Xt[r * 40 + fj * 4]) = h;
        }
#pragma unroll
        for (int p = 0; p < 8; ++p) {
            int idx = p * 256 + tid;
            int q = idx & 3, dd = (idx >> 2) & 31, k = idx >> 7;
            f32x4 v = *(const f32x4*)(
                wg + ((size_t)k * 512 + d0 + dd) * 1024 + f0 + q * 4);
#pragma unroll
            for (int j = 0; j < 4; ++j)
                Bh[(dd * 16 + q * 4 + j) * 24 + k] = (_Float16)v[j];
        }
        __syncthreads();
#pragma unroll
        for (int fl = 0; fl < 4; ++fl) {
            int f_l = w * 4 + fl;
#pragma unroll
            for (int dg = 0; dg < 2; ++dg) {
                half8 a = { 0, 0, 0, 0, 0, 0, 0, 0 };
                if (kc < 2)
                    a = *(const half8*)(&Bh[((dg * 16 + n) * 16 + f_l) * 24 + kc * 8]);
                f32x4 cw = MFMA_F16(a, cf1, zf, 0, 0, 0);
                nsqU[fl] += cw[0] * cw[0] + cw[1] * cw[1]
                          + cw[2] * cw[2] + cw[3] * cw[3];
                half4 h4 = { (_Float16)cw[0], (_Float16)cw[1],
                             (_Float16)cw[2], (_Float16)cw[3] };
                *(half4*)(&Wt[n * 528 + f_l * 32 + dg * 16 + kc * 4]) = h4;
            }
        }
        __syncthreads();
#pragma unroll
        for (int li = 0; li < 4; ++li) {
            int l = w * 4 + li;
            half8 xf = *(const half8*)(&Xt[(l * 16 + n) * 40 + kc * 8]);
            half8 wf = *(const half8*)(&Wt[l * 528 + n * 32 + kc * 8]);
            aU[li] = MFMA_F16(xf, wf, aU[li], 0, 0, 0);
        }
#pragma unroll
        for (int p = 0; p < 8; ++p) {
            int idx = p * 256 + tid;
            int q = idx & 3, dd = (idx >> 2) & 31, k = idx >> 7;
            f32x4 v = *(const f32x4*)(
                wu + ((size_t)k * 512 + d0 + dd) * 1024 + f0 + q * 4);
#pragma unroll
            for (int j = 0; j < 4; ++j)
                Bh[(dd * 16 + q * 4 + j) * 24 + k] = (_Float16)v[j];
        }
        __syncthreads();
#pragma unroll
        for (int fl = 0; fl < 4; ++fl) {
            int f_l = w * 4 + fl;
#pragma unroll
            for (int dg = 0; dg < 2; ++dg) {
                half8 a = { 0, 0, 0, 0, 0, 0, 0, 0 };
                if (kc < 2)
                    a = *(const half8*)(&Bh[((dg * 16 + n) * 16 + f_l) * 24 + kc * 8]);
                f32x4 cw = MFMA_F16(a, cf2, zf, 0, 0, 0);
                nsqV[fl] += cw[0] * cw[0] + cw[1] * cw[1]
                          + cw[2] * cw[2] + cw[3] * cw[3];
                half4 h4 = { (_Float16)cw[0], (_Float16)cw[1],
                             (_Float16)cw[2], (_Float16)cw[3] };
                *(half4*)(&Wt[n * 528 + f_l * 32 + dg * 16 + kc * 4]) = h4;
            }
        }
        __syncthreads();
#pragma unroll
        for (int li = 0; li < 4; ++li) {
            int l = w * 4 + li;
            half8 xf = *(const half8*)(&Xt[(l * 16 + n) * 40 + kc * 8]);
            half8 wf = *(const half8*)(&Wt[l * 528 + n * 32 + kc * 8]);
            aV[li] = MFMA_F16(xf, wf, aV[li], 0, 0, 0);
        }
        __syncthreads();
    }

#pragma unroll
    for (int fl = 0; fl < 4; ++fl) {
        float vU = nsqU[fl], vV = nsqV[fl];
        vU += __shfl_xor(vU, 16); vU += __shfl_xor(vU, 32);
        vV += __shfl_xor(vV, 16); vV += __shfl_xor(vV, 32);
        if (kc == 0) {
            CN[0 * 256 + n * 16 + w * 4 + fl] = vU;
            CN[1 * 256 + n * 16 + w * 4 + fl] = vV;
        }
    }
    __syncthreads();

    int f = f0 + n;
    float usv = fabsf(usp[f]);
    float vsv = fabsf(vsp[f]) * 22.627416997969522f;
#pragma unroll
    for (int li = 0; li < 4; ++li) {
        int lgl = lg * 16 + w * 4 + li;
        float r1 = 1.f / fmaxf(sqrtf(CN[0 * 256 + (w * 4 + li) * 16 + n]), 1e-12f);
        float r2 = 1.f / fmaxf(sqrtf(CN[1 * 256 + (w * 4 + li) * 16 + n]), 1e-12f);
#pragma unroll
        for (int i = 0; i < 4; ++i) {
            float u = aU[li][i] * r1;
            float v = aV[li][i] * r2;
            float zz = vsv * v;
            float sil = zz / (1.f + __expf(-zz));
            float h = sil * (usv * u);
            Hp[((size_t)lgl * 16 + kc * 4 + i) * 1024 + f] = (_Float16)h;
        }
    }
}

__global__ __launch_bounds__(256) void down_kernel(
    const float* __restrict__ wd, const float* __restrict__ tc3,
    const _Float16* __restrict__ Hp, float* __restrict__ out)
{
    int lg = blockIdx.x >> 5;
    int d0 = (blockIdx.x & 31) * 16;
    int tid = threadIdx.x;
    int w = tid >> 6, lane = tid & 63;
    int n = lane & 15, kc = lane >> 4;

    __shared__ __align__(16) _Float16 Ht[256 * 40];
    __shared__ __align__(16) _Float16 Bh[32 * 16 * 24];
    __shared__ __align__(16) _Float16 Wt[16 * 528];
    __shared__ float CN[16 * 16];

    if (tid < 16) {
        const float* row = tc3 + (size_t)(lg * 16 + tid) * 16;
        float e[16], m = -1e30f, sum = 0.f;
#pragma unroll
        for (int k = 0; k < 16; ++k) m = fmaxf(m, row[k]);
#pragma unroll
        for (int k = 0; k < 16; ++k) { e[k] = __expf(row[k] - m); sum += e[k]; }
        float r = 1.f / sum;
#pragma unroll
        for (int k = 0; k < 16; ++k) CN[tid * 16 + k] = e[k] * r;
    }
    __syncthreads();

    half8 cf3 = { 0, 0, 0, 0, 0, 0, 0, 0 };
    if (kc < 2) {
#pragma unroll
        for (int j = 0; j < 8; ++j)
            cf3[j] = (_Float16)CN[n * 16 + kc * 8 + j];
    }

    f32x4 zf = { 0.f, 0.f, 0.f, 0.f };
    f32x4 aO[4];
#pragma unroll
    for (int i = 0; i < 4; ++i) aO[i] = zf;
    float nsqD[4] = { 0.f, 0.f, 0.f, 0.f };

    for (int it = 0; it < 32; ++it) {
        int f0 = it * 32;
#pragma unroll
        for (int p = 0; p < 8; ++p) {
            int r = p * 32 + (tid >> 3);
            int hj = tid & 7;
            int ll = r >> 4, b = r & 15;
            half4 v = *(const half4*)(
                Hp + ((size_t)(lg * 16 + ll) * 16 + b) * 1024 + f0 + hj * 4);
            *(half4*)(&Ht[r * 40 + hj * 4]) = v;
        }
#pragma unroll
        for (int p = 0; p < 8; ++p) {
            int idx = p * 256 + tid;
            int q = idx & 3, ff = (idx >> 2) & 31, k = idx >> 7;
            f32x4 v = *(const f32x4*)(
                wd + ((size_t)k * 1024 + f0 + ff) * 512 + d0 + q * 4);
#pragma unroll
            for (int j = 0; j < 4; ++j)
                Bh[(ff * 16 + q * 4 + j) * 24 + k] = (_Float16)v[j];
        }
        __syncthreads();
#pragma unroll
        for (int dl = 0; dl < 4; ++dl) {
            int d_l = w * 4 + dl;
#pragma unroll
            for (int fg = 0; fg < 2; ++fg) {
                half8 a = { 0, 0, 0, 0, 0, 0, 0, 0 };
                if (kc < 2)
                    a = *(const half8*)(&Bh[((fg * 16 + n) * 16 + d_l) * 24 + kc * 8]);
                f32x4 cw = MFMA_F16(a, cf3, zf, 0, 0, 0);
                nsqD[dl] += cw[0] * cw[0] + cw[1] * cw[1]
                          + cw[2] * cw[2] + cw[3] * cw[3];
                half4 h4 = { (_Float16)cw[0], (_Float16)cw[1],
                             (_Float16)cw[2], (_Float16)cw[3] };
                *(half4*)(&Wt[n * 528 + d_l * 32 + fg * 16 + kc * 4]) = h4;
            }
        }
        __syncthreads();
#pragma unroll
        for (int li = 0; li < 4; ++li) {
            int l = w * 4 + li;
            half8 hf = *(const half8*)(&Ht[(l * 16 + n) * 40 + kc * 8]);
            half8 wf = *(const half8*)(&Wt[l * 528 + n * 32 + kc * 8]);
            aO[li] = MFMA_F16(hf, wf, aO[li], 0, 0, 0);
        }
        __syncthreads();
    }

#pragma unroll
    for (int dl = 0; dl < 4; ++dl) {
        float v = nsqD[dl];
        v += __shfl_xor(v, 16); v += __shfl_xor(v, 32);
        if (kc == 0) CN[n * 16 + w * 4 + dl] = v;
    }
    __syncthreads();

#pragma unroll
    for (int li = 0; li < 4; ++li) {
        int lgl = lg * 16 + w * 4 + li;
        float r3 = 1.f / fmaxf(sqrtf(CN[(w * 4 + li) * 16 + n]), 1e-12f);
#pragma unroll
        for (int i = 0; i < 4; ++i)
            out[((size_t)(kc * 4 + i) * 128 + lgl) * 512 + d0 + n] = aO[li][i] * r3;
    }
}

__global__ __launch_bounds__(128) void final_kernel(float* __restrict__ out)
{
    int rid = blockIdx.x;
    int t = threadIdx.x;
    f32x4 y = *(const f32x4*)(out + (size_t)rid * 512 + t * 4);
    float s = y[0] * y[0] + y[1] * y[1] + y[2] * y[2] + y[3] * y[3];
#pragma unroll
    for (int off = 32; off > 0; off >>= 1) s += __shfl_down(s, off);
    __shared__ float sred[2];
    if ((t & 63) == 0) sred[t >> 6] = s;
    __syncthreads();
    float rr = 1.f / fmaxf(sqrtf(sred[0] + sred[1]), 1e-12f);
    f32x4 o = { y[0] * rr, y[1] * rr, y[2] * rr, y[3] * rr };
    *(f32x4*)(out + (size_t)rid * 512 + t * 4) = o;
}

// ---------------------------------------------------------------------------
extern "C" void kernel_launch(void* const* d_in, const int* in_sizes, int n_in,
                              void* d_out, int out_size, void* d_ws, size_t ws_size,
                              hipStream_t stream)
{
    (void)in_sizes; (void)n_in; (void)out_size;
    const float* x   = (const float*)d_in[0];
    const float* wg  = (const float*)d_in[1];
    const float* wu  = (const float*)d_in[2];
    const float* wd  = (const float*)d_in[3];
    const float* tc1 = (const float*)d_in[4];
    const float* tc2 = (const float*)d_in[5];
    const float* tc3 = (const float*)d_in[6];
    const float* usp = (const float*)d_in[7];
    const float* vsp = (const float*)d_in[8];
    float* outp = (float*)d_out;
    char* ws = (char*)d_ws;

    if (ws_size >= WS_FAST) {
        _Float16* P1 = (_Float16*)(ws + OFF_P1);
        _Float16* P2 = (_Float16*)(ws + OFF_P2);
        _Float16* P3 = (_Float16*)(ws + OFF_P3);
        _Float16* Hp = (_Float16*)(ws + OFF_HP);
        float* Rp = (float*)(ws + OFF_P1);   // overlays P1 (dead after up)
        float* Np = (float*)(ws + OFF_P2);   // overlays P2 (dead after up)
        prep_basis_all<<<dim3(1024, 3), dim3(256), 0, stream>>>(wg, wu, wd,
                                                                P1, P2, P3);
        up_fast<<<dim3(512), dim3(256), 0, stream>>>(P1, P2, x, tc1, tc2,
                                                     usp, vsp, Hp);
        down_fast<<<dim3(1024), dim3(256), 0, stream>>>(P3, tc3, Hp, Rp, Np);
        final_combine<<<dim3(2048), dim3(128), 0, stream>>>(Rp, Np, outp);
    } else {
        _Float16* Hp = (_Float16*)ws;
        up_kernel<<<dim3(512), dim3(256), 0, stream>>>(x, wg, wu, tc1, tc2,
                                                       usp, vsp, Hp);
        down_kernel<<<dim3(256), dim3(256), 0, stream>>>(wd, tc3, Hp, outp);
        final_kernel<<<dim3(2048), dim3(128), 0, stream>>>(outp);
    }
}

// Round 7
// 230.906 us; speedup vs baseline: 1.4351x; 1.4351x over previous
//
#include <hip/hip_runtime.h>
#include <hip/hip_bf16.h>
#include <cmath>

// ---------------------------------------------------------------------------
// NPerTokenSwishGLU_Basis — fused f16-MFMA implementation (gfx950), round 7.
//
// R6 post-mortem: register double-buffer spilled (WRITE_SIZE 4KB->180MB,
// VGPR demand ~220 vs 128 granted). Reverted. R5 residual diagnosed: xf
// loads are 64x128B-line scatters (lane=batch stride 256 KB).
// R7: prep_x materializes XA = f16 x[l][b][d] (2 MB, overlays P3 slot);
// consume A-frags become contiguous 16B/lane loads. P3 prep runs after
// up_fast (XA dead by then) so ws stays at the proven 52 MiB.
// ---------------------------------------------------------------------------

typedef _Float16 half8 __attribute__((ext_vector_type(8)));
typedef _Float16 half4 __attribute__((ext_vector_type(4)));
typedef float    f32x4 __attribute__((ext_vector_type(4)));

#define MFMA_F16 __builtin_amdgcn_mfma_f32_16x16x32_f16

static constexpr size_t OFF_P1 = 0;            // 16 MiB; Rp overlay (down)
static constexpr size_t OFF_P2 = 16777216;     // 16 MiB; Np overlay (down)
static constexpr size_t OFF_P3 = 33554432;     // 16 MiB; XA overlay (up)
static constexpr size_t OFF_HP = 50331648;     // 4 MiB
static constexpr size_t WS_FAST = OFF_HP + 4194304;   // 54,525,952 (proven)

// ---------------------------------------------------------------------------
// prep (two-sided coalesced transpose), z in {0,1,2} via zoff + blockIdx.y:
//   z=0,1: wg/wu (K,512,1024)=[k][d][f] -> P[f][d][k]
//   z=2  : wd    (K,1024,512)=[k][f][d] -> P3[d][f][k]
// ---------------------------------------------------------------------------
__global__ __launch_bounds__(256) void prep_basis_all(
    const float* __restrict__ wg, const float* __restrict__ wu,
    const float* __restrict__ wd,
    _Float16* __restrict__ P1, _Float16* __restrict__ P2,
    _Float16* __restrict__ P3, int zoff)
{
    int z = blockIdx.y + zoff;
    const float* src = (z == 0) ? wg : (z == 1) ? wu : wd;
    _Float16*    dst = (z == 0) ? P1 : (z == 1) ? P2 : P3;
    int Amin = (z == 2) ? 1024 : 512;    // minor-dim size
    int Bmaj = (z == 2) ? 512 : 1024;    // major-dim size
    int nM = Bmaj >> 4;
    int m0 = (blockIdx.x / nM) * 32;     // minor base
    int M0 = (blockIdx.x % nM) * 16;     // major base

    __shared__ float S[16 * 544];        // [k][minor*17 + major]
    int t = threadIdx.x;

    int row = (t >> 2) & 31;
    int cg  = t & 3;
    int khi = t >> 7;
#pragma unroll
    for (int p = 0; p < 8; ++p) {
        int k = p * 2 + khi;
        f32x4 v = *(const f32x4*)(
            src + (size_t)k * Amin * Bmaj + (size_t)(m0 + row) * Bmaj + M0 + cg * 4);
#pragma unroll
        for (int j = 0; j < 4; ++j)
            S[k * 544 + row * 17 + cg * 4 + j] = v[j];
    }
    __syncthreads();

    int mn = t & 31, mjb = t >> 5;
#pragma unroll
    for (int q = 0; q < 2; ++q) {
        int mj = mjb + q * 8;
        half8 v0, v1;
#pragma unroll
        for (int k = 0; k < 8; ++k) v0[k] = (_Float16)S[k * 544 + mn * 17 + mj];
#pragma unroll
        for (int k = 0; k < 8; ++k) v1[k] = (_Float16)S[(k + 8) * 544 + mn * 17 + mj];
        _Float16* out = dst + ((size_t)(M0 + mj) * Amin + m0 + mn) * 16;
        *(half8*)out       = v0;
        *(half8*)(out + 8) = v1;
    }
}

// ---------------------------------------------------------------------------
// prep_x: x fp32 [b][l][d] -> XA f16 [l][b][d]  (both sides coalesced)
// ---------------------------------------------------------------------------
__global__ __launch_bounds__(256) void prep_x(
    const float* __restrict__ x, _Float16* __restrict__ XA)
{
    int idx = blockIdx.x * 256 + threadIdx.x;    // one f32x4 per thread
    int d4 = idx & 127;
    int l  = (idx >> 7) & 127;
    int b  = idx >> 14;
    f32x4 v = *(const f32x4*)(x + ((size_t)(b * 128 + l) * 512 + d4 * 4));
    half4 h = { (_Float16)v[0], (_Float16)v[1], (_Float16)v[2], (_Float16)v[3] };
    *(half4*)(XA + ((size_t)(l * 16 + b) * 512 + d4 * 4)) = h;
}

// ---------------------------------------------------------------------------
// up_fast (R5 body + XA frags): 512 blocks = 8 lg x 64 f-tiles, 256 thr.
// LDS: Wt 2x16x584 (37376 B) + CN 2048 B.
// ---------------------------------------------------------------------------
__global__ __launch_bounds__(256, 2) void up_fast(
    const _Float16* __restrict__ P1, const _Float16* __restrict__ P2,
    const _Float16* __restrict__ XA,
    const float* __restrict__ tc1, const float* __restrict__ tc2,
    const float* __restrict__ usp, const float* __restrict__ vsp,
    _Float16* __restrict__ Hp)
{
    int lg = blockIdx.x >> 6;
    int f0 = (blockIdx.x & 63) * 16;
    int tid = threadIdx.x;
    int w = tid >> 6, lane = tid & 63;
    int n = lane & 15, kc = lane >> 4;

    __shared__ __align__(16) _Float16 Wt[2][16 * 584];  // [mat][l*584+f*36+d]
    __shared__ float CN[2 * 256];

    if (tid < 32) {
        int s = tid >> 4, ll = tid & 15;
        const float* row = (s ? tc2 : tc1) + (size_t)(lg * 16 + ll) * 16;
        float e[16], m = -1e30f, sum = 0.f;
#pragma unroll
        for (int k = 0; k < 16; ++k) m = fmaxf(m, row[k]);
#pragma unroll
        for (int k = 0; k < 16; ++k) { e[k] = __expf(row[k] - m); sum += e[k]; }
        float r = 1.f / sum;
#pragma unroll
        for (int k = 0; k < 16; ++k) CN[s * 256 + ll * 16 + k] = e[k] * r;
    }
    __syncthreads();

    half8 cf1 = { 0, 0, 0, 0, 0, 0, 0, 0 };
    half8 cf2 = { 0, 0, 0, 0, 0, 0, 0, 0 };
    if (kc < 2) {
#pragma unroll
        for (int j = 0; j < 8; ++j) {
            cf1[j] = (_Float16)CN[0 * 256 + n * 16 + kc * 8 + j];
            cf2[j] = (_Float16)CN[1 * 256 + n * 16 + kc * 8 + j];
        }
    }

    f32x4 zf = { 0.f, 0.f, 0.f, 0.f };
    f32x4 aU[4], aV[4];
#pragma unroll
    for (int i = 0; i < 4; ++i) { aU[i] = zf; aV[i] = zf; }
    float nsqU[4] = { 0.f, 0.f, 0.f, 0.f };
    float nsqV[4] = { 0.f, 0.f, 0.f, 0.f };
    half8 xf[4];
    half8 pa[2][4][2];

    for (int it = 0; it < 16; ++it) {
        int d0 = it * 32;
        // ---- Phase A: issue P A-frag loads (contiguous 512 B / inst) ----
#pragma unroll
        for (int m = 0; m < 2; ++m) {
            const _Float16* P = m ? P2 : P1;
#pragma unroll
            for (int fl = 0; fl < 4; ++fl)
#pragma unroll
                for (int dg = 0; dg < 2; ++dg) {
                    half8 a = { 0, 0, 0, 0, 0, 0, 0, 0 };
                    if (kc < 2)
                        a = *(const half8*)(P +
                            ((size_t)(f0 + w * 4 + fl) * 512 + d0 + dg * 16 + n) * 16 + kc * 8);
                    pa[m][fl][dg] = a;
                }
        }
        // ---- consume(it-1) from Wt ----
        if (it > 0) {
#pragma unroll
            for (int li = 0; li < 4; ++li) {
                int l = w * 4 + li;
                half8 wU = *(const half8*)(&Wt[0][l * 584 + n * 36 + kc * 8]);
                half8 wV = *(const half8*)(&Wt[1][l * 584 + n * 36 + kc * 8]);
                aU[li] = MFMA_F16(xf[li], wU, aU[li], 0, 0, 0);
                aV[li] = MFMA_F16(xf[li], wV, aV[li], 0, 0, 0);
            }
        }
        // ---- prefetch x frags (f16, contiguous 16 B/lane) ----
#pragma unroll
        for (int li = 0; li < 4; ++li) {
            int l = lg * 16 + w * 4 + li;
            xf[li] = *(const half8*)(XA + ((size_t)l * 16 + n) * 512 + d0 + kc * 8);
        }
        __syncthreads();
        // ---- Phase B: mix(it) -> Wt (+nsq) ----
#pragma unroll
        for (int fl = 0; fl < 4; ++fl) {
            int f_l = w * 4 + fl;
#pragma unroll
            for (int dg = 0; dg < 2; ++dg) {
                f32x4 c1 = MFMA_F16(pa[0][fl][dg], cf1, zf, 0, 0, 0);
                nsqU[fl] += c1[0] * c1[0] + c1[1] * c1[1]
                          + c1[2] * c1[2] + c1[3] * c1[3];
                half4 h1 = { (_Float16)c1[0], (_Float16)c1[1],
                             (_Float16)c1[2], (_Float16)c1[3] };
                *(half4*)(&Wt[0][n * 584 + f_l * 36 + dg * 16 + kc * 4]) = h1;
                f32x4 c2 = MFMA_F16(pa[1][fl][dg], cf2, zf, 0, 0, 0);
                nsqV[fl] += c2[0] * c2[0] + c2[1] * c2[1]
                          + c2[2] * c2[2] + c2[3] * c2[3];
                half4 h2 = { (_Float16)c2[0], (_Float16)c2[1],
                             (_Float16)c2[2], (_Float16)c2[3] };
                *(half4*)(&Wt[1][n * 584 + f_l * 36 + dg * 16 + kc * 4]) = h2;
            }
        }
        __syncthreads();
    }
    // ---- tail consume (chunk 15) ----
#pragma unroll
    for (int li = 0; li < 4; ++li) {
        int l = w * 4 + li;
        half8 wU = *(const half8*)(&Wt[0][l * 584 + n * 36 + kc * 8]);
        half8 wV = *(const half8*)(&Wt[1][l * 584 + n * 36 + kc * 8]);
        aU[li] = MFMA_F16(xf[li], wU, aU[li], 0, 0, 0);
        aV[li] = MFMA_F16(xf[li], wV, aV[li], 0, 0, 0);
    }

    // ---- norms reduce ----
#pragma unroll
    for (int fl = 0; fl < 4; ++fl) {
        float vU = nsqU[fl], vV = nsqV[fl];
        vU += __shfl_xor(vU, 16); vU += __shfl_xor(vU, 32);
        vV += __shfl_xor(vV, 16); vV += __shfl_xor(vV, 32);
        if (kc == 0) {
            CN[0 * 256 + n * 16 + w * 4 + fl] = vU;
            CN[1 * 256 + n * 16 + w * 4 + fl] = vV;
        }
    }
    __syncthreads();

    int f = f0 + n;
    float usv = fabsf(usp[f]);
    float vsv = fabsf(vsp[f]) * 22.627416997969522f;   // sqrt(512)
#pragma unroll
    for (int li = 0; li < 4; ++li) {
        int lgl = lg * 16 + w * 4 + li;
        float r1 = 1.f / fmaxf(sqrtf(CN[0 * 256 + (w * 4 + li) * 16 + n]), 1e-12f);
        float r2 = 1.f / fmaxf(sqrtf(CN[1 * 256 + (w * 4 + li) * 16 + n]), 1e-12f);
#pragma unroll
        for (int i = 0; i < 4; ++i) {
            float u = aU[li][i] * r1;
            float v = aV[li][i] * r2;
            float zz = vsv * v;
            float sil = zz / (1.f + __expf(-zz));
            float h = sil * (usv * u);
            Hp[((size_t)lgl * 16 + kc * 4 + i) * 1024 + f] = (_Float16)h;
        }
    }
}

// ---------------------------------------------------------------------------
// down_fast (R5, unchanged): 1024 blocks = 4 f-quarters x 8 lg x 32 d-tiles.
// ---------------------------------------------------------------------------
__global__ __launch_bounds__(256, 2) void down_fast(
    const _Float16* __restrict__ P3, const float* __restrict__ tc3,
    const _Float16* __restrict__ Hp,
    float* __restrict__ Rp, float* __restrict__ Np)
{
    int zh = blockIdx.x >> 8;          // 0..3
    int rem = blockIdx.x & 255;
    int lg = rem >> 5;
    int d0 = (rem & 31) * 16;
    int tid = threadIdx.x;
    int w = tid >> 6, lane = tid & 63;
    int n = lane & 15, kc = lane >> 4;

    __shared__ __align__(16) _Float16 Wt[16 * 584];    // [l*584 + d*36 + f]
    __shared__ float CN[256];

    if (tid < 16) {
        const float* row = tc3 + (size_t)(lg * 16 + tid) * 16;
        float e[16], m = -1e30f, sum = 0.f;
#pragma unroll
        for (int k = 0; k < 16; ++k) m = fmaxf(m, row[k]);
#pragma unroll
        for (int k = 0; k < 16; ++k) { e[k] = __expf(row[k] - m); sum += e[k]; }
        float r = 1.f / sum;
#pragma unroll
        for (int k = 0; k < 16; ++k) CN[tid * 16 + k] = e[k] * r;
    }
    __syncthreads();

    half8 cf3 = { 0, 0, 0, 0, 0, 0, 0, 0 };
    if (kc < 2) {
#pragma unroll
        for (int j = 0; j < 8; ++j)
            cf3[j] = (_Float16)CN[n * 16 + kc * 8 + j];
    }

    f32x4 zf = { 0.f, 0.f, 0.f, 0.f };
    f32x4 aO[4];
#pragma unroll
    for (int i = 0; i < 4; ++i) aO[i] = zf;
    float nsqD[4] = { 0.f, 0.f, 0.f, 0.f };
    half8 hf[4];
    half8 pa[4][2];

    for (int it = 0; it < 8; ++it) {
        int f0 = zh * 256 + it * 32;
#pragma unroll
        for (int dl = 0; dl < 4; ++dl) {
#pragma unroll
            for (int fg = 0; fg < 2; ++fg) {
                half8 a = { 0, 0, 0, 0, 0, 0, 0, 0 };
                if (kc < 2)
                    a = *(const half8*)(P3 +
                        ((size_t)(d0 + w * 4 + dl) * 1024 + f0 + fg * 16 + n) * 16 + kc * 8);
                pa[dl][fg] = a;
            }
        }
        if (it > 0) {
#pragma unroll
            for (int li = 0; li < 4; ++li) {
                int l = w * 4 + li;
                half8 wf = *(const half8*)(&Wt[l * 584 + n * 36 + kc * 8]);
                aO[li] = MFMA_F16(hf[li], wf, aO[li], 0, 0, 0);
            }
        }
#pragma unroll
        for (int li = 0; li < 4; ++li) {
            int l = lg * 16 + w * 4 + li;
            hf[li] = *(const half8*)(Hp + ((size_t)l * 16 + n) * 1024 + f0 + kc * 8);
        }
        __syncthreads();
#pragma unroll
        for (int dl = 0; dl < 4; ++dl) {
            int d_l = w * 4 + dl;
#pragma unroll
            for (int fg = 0; fg < 2; ++fg) {
                f32x4 cw = MFMA_F16(pa[dl][fg], cf3, zf, 0, 0, 0);
                nsqD[dl] += cw[0] * cw[0] + cw[1] * cw[1]
                          + cw[2] * cw[2] + cw[3] * cw[3];
                half4 h4 = { (_Float16)cw[0], (_Float16)cw[1],
                             (_Float16)cw[2], (_Float16)cw[3] };
                *(half4*)(&Wt[n * 584 + d_l * 36 + fg * 16 + kc * 4]) = h4;
            }
        }
        __syncthreads();
    }
#pragma unroll
    for (int li = 0; li < 4; ++li) {
        int l = w * 4 + li;
        half8 wf = *(const half8*)(&Wt[l * 584 + n * 36 + kc * 8]);
        aO[li] = MFMA_F16(hf[li], wf, aO[li], 0, 0, 0);
    }

#pragma unroll
    for (int dl = 0; dl < 4; ++dl) {
        float v = nsqD[dl];
        v += __shfl_xor(v, 16); v += __shfl_xor(v, 32);
        if (kc == 0)
            Np[(size_t)zh * 65536 + (size_t)(lg * 16 + n) * 512 + d0 + w * 4 + dl] = v;
    }
#pragma unroll
    for (int li = 0; li < 4; ++li) {
        int lgl = lg * 16 + w * 4 + li;
#pragma unroll
        for (int i = 0; i < 4; ++i)
            Rp[(size_t)zh * 1048576 +
               ((size_t)(kc * 4 + i) * 128 + lgl) * 512 + d0 + n] = aO[li][i];
    }
}

// ---------------------------------------------------------------------------
__global__ __launch_bounds__(128) void final_combine(
    const float* __restrict__ Rp, const float* __restrict__ Np,
    float* __restrict__ out)
{
    int rid = blockIdx.x;              // b*128 + l
    int l = rid & 127;
    int t = threadIdx.x;
    f32x4 r = { 0.f, 0.f, 0.f, 0.f };
    f32x4 nn = { 0.f, 0.f, 0.f, 0.f };
#pragma unroll
    for (int zh = 0; zh < 4; ++zh) {
        f32x4 rz = *(const f32x4*)(Rp + (size_t)zh * 1048576 + (size_t)rid * 512 + t * 4);
        f32x4 nz = *(const f32x4*)(Np + (size_t)zh * 65536 + (size_t)l * 512 + t * 4);
#pragma unroll
        for (int j = 0; j < 4; ++j) { r[j] += rz[j]; nn[j] += nz[j]; }
    }
    f32x4 y;
#pragma unroll
    for (int j = 0; j < 4; ++j) {
        float rr = 1.f / fmaxf(sqrtf(fmaxf(nn[j], 0.f)), 1e-12f);
        y[j] = r[j] * rr;
    }
    float s = y[0] * y[0] + y[1] * y[1] + y[2] * y[2] + y[3] * y[3];
#pragma unroll
    for (int off = 32; off > 0; off >>= 1) s += __shfl_down(s, off);
    __shared__ float sred[2];
    if ((t & 63) == 0) sred[t >> 6] = s;
    __syncthreads();
    float rr = 1.f / fmaxf(sqrtf(sred[0] + sred[1]), 1e-12f);
    f32x4 o = { y[0] * rr, y[1] * rr, y[2] * rr, y[3] * rr };
    *(f32x4*)(out + (size_t)rid * 512 + t * 4) = o;
}

// ===========================================================================
// SLOW FALLBACK (round-2 kernels, proven) — used when ws_size < WS_FAST
// ===========================================================================
__global__ __launch_bounds__(256) void up_kernel(
    const float* __restrict__ x,
    const float* __restrict__ wg, const float* __restrict__ wu,
    const float* __restrict__ tc1, const float* __restrict__ tc2,
    const float* __restrict__ usp, const float* __restrict__ vsp,
    _Float16* __restrict__ Hp)
{
    int lg = blockIdx.x >> 6;
    int f0 = (blockIdx.x & 63) * 16;
    int tid = threadIdx.x;
    int w = tid >> 6, lane = tid & 63;
    int n = lane & 15, kc = lane >> 4;

    __shared__ __align__(16) _Float16 Xt[256 * 40];
    __shared__ __align__(16) _Float16 Bh[32 * 16 * 24];
    __shared__ __align__(16) _Float16 Wt[16 * 528];
    __shared__ float CN[2 * 16 * 16];

    if (tid < 32) {
        int s = tid >> 4, ll = tid & 15;
        const float* row = (s ? tc2 : tc1) + (size_t)(lg * 16 + ll) * 16;
        float e[16], m = -1e30f, sum = 0.f;
#pragma unroll
        for (int k = 0; k < 16; ++k) m = fmaxf(m, row[k]);
#pragma unroll
        for (int k = 0; k < 16; ++k) { e[k] = __expf(row[k] - m); sum += e[k]; }
        float r = 1.f / sum;
#pragma unroll
        for (int k = 0; k < 16; ++k) CN[s * 256 + ll * 16 + k] = e[k] * r;
    }
    __syncthreads();

    half8 cf1 = { 0, 0, 0, 0, 0, 0, 0, 0 };
    half8 cf2 = { 0, 0, 0, 0, 0, 0, 0, 0 };
    if (kc < 2) {
#pragma unroll
        for (int j = 0; j < 8; ++j) {
            cf1[j] = (_Float16)CN[0 * 256 + n * 16 + kc * 8 + j];
            cf2[j] = (_Float16)CN[1 * 256 + n * 16 + kc * 8 + j];
        }
    }

    f32x4 zf = { 0.f, 0.f, 0.f, 0.f };
    f32x4 aU[4], aV[4];
#pragma unroll
    for (int i = 0; i < 4; ++i) { aU[i] = zf; aV[i] = zf; }
    float nsqU[4] = { 0.f, 0.f, 0.f, 0.f };
    float nsqV[4] = { 0.f, 0.f, 0.f, 0.f };

    for (int it = 0; it < 16; ++it) {
        int d0 = it * 32;
#pragma unroll
        for (int p = 0; p < 8; ++p) {
            int r = p * 32 + (tid >> 3);
            int fj = tid & 7;
            int ll = r >> 4, b = r & 15;
            f32x4 v = *(const f32x4*)(
                x + ((size_t)(b * 128 + lg * 16 + ll) * 512 + d0 + fj * 4));
            half4 h = { (_Float16)v[0], (_Float16)v[1],
                        (_Float16)v[2], (_Float16)v[3] };
            *(half4*)(&Xt[r * 40 + fj * 4]) = h;
        }
#pragma unroll
        for (int p = 0; p < 8; ++p) {
            int idx = p * 256 + tid;
            int q = idx & 3, dd = (idx >> 2) & 31, k = idx >> 7;
            f32x4 v = *(const f32x4*)(
                wg + ((size_t)k * 512 + d0 + dd) * 1024 + f0 + q * 4);
#pragma unroll
            for (int j = 0; j < 4; ++j)
                Bh[(dd * 16 + q * 4 + j) * 24 + k] = (_Float16)v[j];
        }
        __syncthreads();
#pragma unroll
        for (int fl = 0; fl < 4; ++fl) {
            int f_l = w * 4 + fl;
#pragma unroll
            for (int dg = 0; dg < 2; ++dg) {
                half8 a = { 0, 0, 0, 0, 0, 0, 0, 0 };
                if (kc < 2)
                    a = *(const half8*)(&Bh[((dg * 16 + n) * 16 + f_l) * 24 + kc * 8]);
                f32x4 cw = MFMA_F16(a, cf1, zf, 0, 0, 0);
                nsqU[fl] += cw[0] * cw[0] + cw[1] * cw[1]
                          + cw[2] * cw[2] + cw[3] * cw[3];
                half4 h4 = { (_Float16)cw[0], (_Float16)cw[1],
                             (_Float16)cw[2], (_Float16)cw[3] };
                *(half4*)(&Wt[n * 528 + f_l * 32 + dg * 16 + kc * 4]) = h4;
            }
        }
        __syncthreads();
#pragma unroll
        for (int li = 0; li < 4; ++li) {
            int l = w * 4 + li;
            half8 xf = *(const half8*)(&Xt[(l * 16 + n) * 40 + kc * 8]);
            half8 wf = *(const half8*)(&Wt[l * 528 + n * 32 + kc * 8]);
            aU[li] = MFMA_F16(xf, wf, aU[li], 0, 0, 0);
        }
#pragma unroll
        for (int p = 0; p < 8; ++p) {
            int idx = p * 256 + tid;
            int q = idx & 3, dd = (idx >> 2) & 31, k = idx >> 7;
            f32x4 v = *(const f32x4*)(
                wu + ((size_t)k * 512 + d0 + dd) * 1024 + f0 + q * 4);
#pragma unroll
            for (int j = 0; j < 4; ++j)
                Bh[(dd * 16 + q * 4 + j) * 24 + k] = (_Float16)v[j];
        }
        __syncthreads();
#pragma unroll
        for (int fl = 0; fl < 4; ++fl) {
            int f_l = w * 4 + fl;
#pragma unroll
            for (int dg = 0; dg < 2; ++dg) {
                half8 a = { 0, 0, 0, 0, 0, 0, 0, 0 };
                if (kc < 2)
                    a = *(const half8*)(&Bh[((dg * 16 + n) * 16 + f_l) * 24 + kc * 8]);
                f32x4 cw = MFMA_F16(a, cf2, zf, 0, 0, 0);
                nsqV[fl] += cw[0] * cw[0] + cw[1] * cw[1]
                          + cw[2] * cw[2] + cw[3] * cw[3];
                half4 h4 = { (_Float16)cw[0], (_Float16)cw[1],
                             (_Float16)cw[2], (_Float16)cw[3] };
                *(half4*)(&Wt[n * 528 + f_l * 32 + dg * 16 + kc * 4]) = h4;
            }
        }
        __syncthreads();
#pragma unroll
        for (int li = 0; li < 4; ++li) {
            int l = w * 4 + li;
            half8 xf = *(const half8*)(&Xt[(l * 16 + n) * 40 + kc * 8]);
            half8 wf = *(const half8*)(&Wt[l * 528 + n * 32 + kc * 8]);
            aV[li] = MFMA_F16(xf, wf, aV[li], 0, 0, 0);
        }
        __syncthreads();
    }

#pragma unroll
    for (int fl = 0; fl < 4; ++fl) {
        float vU = nsqU[fl], vV = nsqV[fl];
        vU += __shfl_xor(vU, 16); vU += __shfl_xor(vU, 32);
        vV += __shfl_xor(vV, 16); vV += __shfl_xor(vV, 32);
        if (kc == 0) {
            CN[0 * 256 + n * 16 + w * 4 + fl] = vU;
            CN[1 * 256 + n * 16 + w * 4 + fl] = vV;
        }
    }
    __syncthreads();

    int f = f0 + n;
    float usv = fabsf(usp[f]);
    float vsv = fabsf(vsp[f]) * 22.627416997969522f;
#pragma unroll
    for (int li = 0; li < 4; ++li) {
        int lgl = lg * 16 + w * 4 + li;
        float r1 = 1.f / fmaxf(sqrtf(CN[0 * 256 + (w * 4 + li) * 16 + n]), 1e-12f);
        float r2 = 1.f / fmaxf(sqrtf(CN[1 * 256 + (w * 4 + li) * 16 + n]), 1e-12f);
#pragma unroll
        for (int i = 0; i < 4; ++i) {
            float u = aU[li][i] * r1;
            float v = aV[li][i] * r2;
            float zz = vsv * v;
            float sil = zz / (1.f + __expf(-zz));
            float h = sil * (usv * u);
            Hp[((size_t)lgl * 16 + kc * 4 + i) * 1024 + f] = (_Float16)h;
        }
    }
}

__global__ __launch_bounds__(256) void down_kernel(
    const float* __restrict__ wd, const float* __restrict__ tc3,
    const _Float16* __restrict__ Hp, float* __restrict__ out)
{
    int lg = blockIdx.x >> 5;
    int d0 = (blockIdx.x & 31) * 16;
    int tid = threadIdx.x;
    int w = tid >> 6, lane = tid & 63;
    int n = lane & 15, kc = lane >> 4;

    __shared__ __align__(16) _Float16 Ht[256 * 40];
    __shared__ __align__(16) _Float16 Bh[32 * 16 * 24];
    __shared__ __align__(16) _Float16 Wt[16 * 528];
    __shared__ float CN[16 * 16];

    if (tid < 16) {
        const float* row = tc3 + (size_t)(lg * 16 + tid) * 16;
        float e[16], m = -1e30f, sum = 0.f;
#pragma unroll
        for (int k = 0; k < 16; ++k) m = fmaxf(m, row[k]);
#pragma unroll
        for (int k = 0; k < 16; ++k) { e[k] = __expf(row[k] - m); sum += e[k]; }
        float r = 1.f / sum;
#pragma unroll
        for (int k = 0; k < 16; ++k) CN[tid * 16 + k] = e[k] * r;
    }
    __syncthreads();

    half8 cf3 = { 0, 0, 0, 0, 0, 0, 0, 0 };
    if (kc < 2) {
#pragma unroll
        for (int j = 0; j < 8; ++j)
            cf3[j] = (_Float16)CN[n * 16 + kc * 8 + j];
    }

    f32x4 zf = { 0.f, 0.f, 0.f, 0.f };
    f32x4 aO[4];
#pragma unroll
    for (int i = 0; i < 4; ++i) aO[i] = zf;
    float nsqD[4] = { 0.f, 0.f, 0.f, 0.f };

    for (int it = 0; it < 32; ++it) {
        int f0 = it * 32;
#pragma unroll
        for (int p = 0; p < 8; ++p) {
            int r = p * 32 + (tid >> 3);
            int hj = tid & 7;
            int ll = r >> 4, b = r & 15;
            half4 v = *(const half4*)(
                Hp + ((size_t)(lg * 16 + ll) * 16 + b) * 1024 + f0 + hj * 4);
            *(half4*)(&Ht[r * 40 + hj * 4]) = v;
        }
#pragma unroll
        for (int p = 0; p < 8; ++p) {
            int idx = p * 256 + tid;
            int q = idx & 3, ff = (idx >> 2) & 31, k = idx >> 7;
            f32x4 v = *(const f32x4*)(
                wd + ((size_t)k * 1024 + f0 + ff) * 512 + d0 + q * 4);
#pragma unroll
            for (int j = 0; j < 4; ++j)
                Bh[(ff * 16 + q * 4 + j) * 24 + k] = (_Float16)v[j];
        }
        __syncthreads();
#pragma unroll
        for (int dl = 0; dl < 4; ++dl) {
            int d_l = w * 4 + dl;
#pragma unroll
            for (int fg = 0; fg < 2; ++fg) {
                half8 a = { 0, 0, 0, 0, 0, 0, 0, 0 };
                if (kc < 2)
                    a = *(const half8*)(&Bh[((fg * 16 + n) * 16 + d_l) * 24 + kc * 8]);
                f32x4 cw = MFMA_F16(a, cf3, zf, 0, 0, 0);
                nsqD[dl] += cw[0] * cw[0] + cw[1] * cw[1]
                          + cw[2] * cw[2] + cw[3] * cw[3];
                half4 h4 = { (_Float16)cw[0], (_Float16)cw[1],
                             (_Float16)cw[2], (_Float16)cw[3] };
                *(half4*)(&Wt[n * 528 + d_l * 32 + fg * 16 + kc * 4]) = h4;
            }
        }
        __syncthreads();
#pragma unroll
        for (int li = 0; li < 4; ++li) {
            int l = w * 4 + li;
            half8 hf = *(const half8*)(&Ht[(l * 16 + n) * 40 + kc * 8]);
            half8 wf = *(const half8*)(&Wt[l * 528 + n * 32 + kc * 8]);
            aO[li] = MFMA_F16(hf, wf, aO[li], 0, 0, 0);
        }
        __syncthreads();
    }

#pragma unroll
    for (int dl = 0; dl < 4; ++dl) {
        float v = nsqD[dl];
        v += __shfl_xor(v, 16); v += __shfl_xor(v, 32);
        if (kc == 0) CN[n * 16 + w * 4 + dl] = v;
    }
    __syncthreads();

#pragma unroll
    for (int li = 0; li < 4; ++li) {
        int lgl = lg * 16 + w * 4 + li;
        float r3 = 1.f / fmaxf(sqrtf(CN[(w * 4 + li) * 16 + n]), 1e-12f);
#pragma unroll
        for (int i = 0; i < 4; ++i)
            out[((size_t)(kc * 4 + i) * 128 + lgl) * 512 + d0 + n] = aO[li][i] * r3;
    }
}

__global__ __launch_bounds__(128) void final_kernel(float* __restrict__ out)
{
    int rid = blockIdx.x;
    int t = threadIdx.x;
    f32x4 y = *(const f32x4*)(out + (size_t)rid * 512 + t * 4);
    float s = y[0] * y[0] + y[1] * y[1] + y[2] * y[2] + y[3] * y[3];
#pragma unroll
    for (int off = 32; off > 0; off >>= 1) s += __shfl_down(s, off);
    __shared__ float sred[2];
    if ((t & 63) == 0) sred[t >> 6] = s;
    __syncthreads();
    float rr = 1.f / fmaxf(sqrtf(sred[0] + sred[1]), 1e-12f);
    f32x4 o = { y[0] * rr, y[1] * rr, y[2] * rr, y[3] * rr };
    *(f32x4*)(out + (size_t)rid * 512 + t * 4) = o;
}

// ---------------------------------------------------------------------------
extern "C" void kernel_launch(void* const* d_in, const int* in_sizes, int n_in,
                              void* d_out, int out_size, void* d_ws, size_t ws_size,
                              hipStream_t stream)
{
    (void)in_sizes; (void)n_in; (void)out_size;
    const float* x   = (const float*)d_in[0];
    const float* wg  = (const float*)d_in[1];
    const float* wu  = (const float*)d_in[2];
    const float* wd  = (const float*)d_in[3];
    const float* tc1 = (const float*)d_in[4];
    const float* tc2 = (const float*)d_in[5];
    const float* tc3 = (const float*)d_in[6];
    const float* usp = (const float*)d_in[7];
    const float* vsp = (const float*)d_in[8];
    float* outp = (float*)d_out;
    char* ws = (char*)d_ws;

    if (ws_size >= WS_FAST) {
        _Float16* P1 = (_Float16*)(ws + OFF_P1);
        _Float16* P2 = (_Float16*)(ws + OFF_P2);
        _Float16* P3 = (_Float16*)(ws + OFF_P3);
        _Float16* XA = (_Float16*)(ws + OFF_P3);   // overlays P3 slot (up only)
        _Float16* Hp = (_Float16*)(ws + OFF_HP);
        float* Rp = (float*)(ws + OFF_P1);   // overlays P1 (dead after up)
        float* Np = (float*)(ws + OFF_P2);   // overlays P2 (dead after up)
        prep_basis_all<<<dim3(1024, 2), dim3(256), 0, stream>>>(
            wg, wu, wd, P1, P2, P3, 0);                    // P1, P2
        prep_x<<<dim3(1024), dim3(256), 0, stream>>>(x, XA);
        up_fast<<<dim3(512), dim3(256), 0, stream>>>(P1, P2, XA, tc1, tc2,
                                                     usp, vsp, Hp);
        prep_basis_all<<<dim3(1024, 1), dim3(256), 0, stream>>>(
            wg, wu, wd, P1, P2, P3, 2);                    // P3 (over XA)
        down_fast<<<dim3(1024), dim3(256), 0, stream>>>(P3, tc3, Hp, Rp, Np);
        final_combine<<<dim3(2048), dim3(128), 0, stream>>>(Rp, Np, outp);
    } else {
        _Float16* Hp = (_Float16*)ws;
        up_kernel<<<dim3(512), dim3(256), 0, stream>>>(x, wg, wu, tc1, tc2,
                                                       usp, vsp, Hp);
        down_kernel<<<dim3(256), dim3(256), 0, stream>>>(wd, tc3, Hp, outp);
        final_kernel<<<dim3(2048), dim3(128), 0, stream>>>(outp);
    }
}